// Round 1
// 862.949 us; speedup vs baseline: 1.0031x; 1.0031x over previous
//
#include <hip/hip_runtime.h>
#include <math.h>

#define N_NODES 50000
#define N_EDGES 1600000
#define HIDDEN  128
#define DC      16      // number of RBF centers
#define EPB     64      // edges per block
#define BLOCK   256
#define RBF_LD  20      // padded leading dim (floats): 80 B, 16B-aligned; stride 20
                        // makes the two per-wave broadcast rows land on different banks

// mu_k = k * 6/15 = k * 0.4   (linspace(0,6,16) is endpoint-inclusive!)
// sigma = (6-0)/16 = 0.375 -> inv_sigma = 8/3
#define MU_STEP   0.4f
#define INV_SIGMA 2.6666666666666665f

typedef float f32x4 __attribute__((ext_vector_type(4)));

__device__ __forceinline__ float fast_sigmoid(float x) {
    float e = __expf(-x);                       // v_mul + v_exp_f32
    return __builtin_amdgcn_rcpf(1.0f + e);     // v_rcp_f32 (~1 ulp, fine at 2% tol)
}

__device__ __forceinline__ float4 fma4(float s, float4 w, float4 a) {
    a.x = fmaf(s, w.x, a.x);
    a.y = fmaf(s, w.y, a.y);
    a.z = fmaf(s, w.z, a.z);
    a.w = fmaf(s, w.w, a.w);
    return a;
}

__global__ __launch_bounds__(BLOCK, 4) void edge_attr_kernel(
    const float* __restrict__ pos,        // [N_NODES, 3]
    const int* __restrict__ ei,           // [2, N_EDGES] (harness delivers int32)
    const float* __restrict__ W,          // [DC, HIDDEN]
    const float* __restrict__ b,          // [HIDDEN]
    float* __restrict__ out)              // [N_EDGES, HIDDEN]
{
    // rbf tile stored row-per-edge so phase-2 can read all 16 features with
    // 4x ds_read_b128 (broadcast within each half-wave). Padded to 20 floats:
    // 16B alignment kept, and rows el / el+1 differ by 20 banks -> the two
    // distinct addresses per wave read instr never collide.
    __shared__ float rbf_s[EPB][RBF_LD];

    const int tid = threadIdx.x;
    const int h4  = tid & 31;   // which float4 chunk of the 128 hidden cols
    const int eo  = tid >> 5;   // 0..7 : edge-row offset within the block

    // ---- W columns into registers (L1-broadcast loads, 8 threads share addr)
    float4 wcol[DC];
    #pragma unroll
    for (int k = 0; k < DC; ++k)
        wcol[k] = *reinterpret_cast<const float4*>(W + k * HIDDEN + h4 * 4);
    const float4 bias = *reinterpret_cast<const float4*>(b + h4 * 4);

    // ---- Phase 1: RBF features for this block's 64 edges
    {
        const int el = tid & 63;          // edge within block
        const int kg = tid >> 6;          // 0..3 -> k = kg*4 .. kg*4+3
        const int e = blockIdx.x * EPB + el;
        const int s = ei[e];
        const int d = ei[N_EDGES + e];
        const float dx = pos[3 * s + 0] - pos[3 * d + 0];
        const float dy = pos[3 * s + 1] - pos[3 * d + 1];
        const float dz = pos[3 * s + 2] - pos[3 * d + 2];
        const float dist = sqrtf(dx * dx + dy * dy + dz * dz);
        float4 rv;
        {
            const float t0 = (dist - MU_STEP * (float)(kg * 4 + 0)) * INV_SIGMA;
            const float t1 = (dist - MU_STEP * (float)(kg * 4 + 1)) * INV_SIGMA;
            const float t2 = (dist - MU_STEP * (float)(kg * 4 + 2)) * INV_SIGMA;
            const float t3 = (dist - MU_STEP * (float)(kg * 4 + 3)) * INV_SIGMA;
            rv.x = __expf(-t0 * t0);
            rv.y = __expf(-t1 * t1);
            rv.z = __expf(-t2 * t2);
            rv.w = __expf(-t3 * t3);
        }
        // one ds_write_b128 per thread (addr = el*80 + kg*16, 16B aligned)
        *reinterpret_cast<float4*>(&rbf_s[el][kg * 4]) = rv;
    }
    __syncthreads();

    // ---- Phase 2: out[e][h] = sigmoid(sum_k rbf[k] * W[k][h] + b[h])
    const size_t row0 = (size_t)blockIdx.x * EPB;
    #pragma unroll
    for (int i = 0; i < EPB / 8; ++i) {
        const int el = eo + i * 8;

        // 4x ds_read_b128: half-wave broadcast, rows differ by 20 banks
        const float4* rp = reinterpret_cast<const float4*>(&rbf_s[el][0]);
        const float4 ra = rp[0];
        const float4 rb = rp[1];
        const float4 rc = rp[2];
        const float4 rd = rp[3];

        float4 acc = bias;
        acc = fma4(ra.x, wcol[0],  acc);
        acc = fma4(ra.y, wcol[1],  acc);
        acc = fma4(ra.z, wcol[2],  acc);
        acc = fma4(ra.w, wcol[3],  acc);
        acc = fma4(rb.x, wcol[4],  acc);
        acc = fma4(rb.y, wcol[5],  acc);
        acc = fma4(rb.z, wcol[6],  acc);
        acc = fma4(rb.w, wcol[7],  acc);
        acc = fma4(rc.x, wcol[8],  acc);
        acc = fma4(rc.y, wcol[9],  acc);
        acc = fma4(rc.z, wcol[10], acc);
        acc = fma4(rc.w, wcol[11], acc);
        acc = fma4(rd.x, wcol[12], acc);
        acc = fma4(rd.y, wcol[13], acc);
        acc = fma4(rd.z, wcol[14], acc);
        acc = fma4(rd.w, wcol[15], acc);

        acc.x = fast_sigmoid(acc.x);
        acc.y = fast_sigmoid(acc.y);
        acc.z = fast_sigmoid(acc.z);
        acc.w = fast_sigmoid(acc.w);

        // nontemporal: out is write-once, never re-read -> keep it from
        // evicting the pos table out of L2 (kills the ~300MB pos re-fetch)
        __builtin_nontemporal_store(*reinterpret_cast<f32x4*>(&acc),
            reinterpret_cast<f32x4*>(out + (row0 + el) * HIDDEN + h4 * 4));
    }
}

extern "C" void kernel_launch(void* const* d_in, const int* in_sizes, int n_in,
                              void* d_out, int out_size, void* d_ws, size_t ws_size,
                              hipStream_t stream) {
    const float* pos = (const float*)d_in[0];
    const int*   ei  = (const int*)d_in[1];     // harness delivers integers as int32
    const float* W   = (const float*)d_in[2];
    const float* b   = (const float*)d_in[3];
    float*       out = (float*)d_out;

    dim3 grid(N_EDGES / EPB);   // 1,600,000 / 64 = 25,000 blocks exactly
    edge_attr_kernel<<<grid, BLOCK, 0, stream>>>(pos, ei, W, b, out);
}

// Round 2
// 824.252 us; speedup vs baseline: 1.0502x; 1.0469x over previous
//
#include <hip/hip_runtime.h>
#include <math.h>

#define N_NODES 50000
#define N_EDGES 1600000
#define HIDDEN  128
#define DC      16      // number of RBF centers
#define EPB     128     // edges per block
#define BLOCK   256
#define RBF_LD  20      // padded leading dim: 80 B rows, keeps 16B alignment

// mu_k = k * 6/15 = k * 0.4   (linspace(0,6,16) is endpoint-inclusive!)
// sigma = (6-0)/16 = 0.375 -> inv_sigma = 8/3
#define MU_STEP   0.4f
#define INV_SIGMA 2.6666666666666665f

typedef float f32x2 __attribute__((ext_vector_type(2)));
typedef float f32x4 __attribute__((ext_vector_type(4)));
// pos rows are 12 B so float4 endpoint loads are only 4B-aligned; declare that.
typedef f32x4 f32x4u __attribute__((aligned(4)));

__device__ __forceinline__ float fast_sigmoid(float x) {
    float e = __expf(-x);                       // v_mul + v_exp_f32
    return __builtin_amdgcn_rcpf(1.0f + e);     // v_rcp_f32 (~1 ulp, fine at tol)
}

__device__ __forceinline__ f32x2 fma2(float s, f32x2 w, f32x2 a) {
    a.x = fmaf(s, w.x, a.x);
    a.y = fmaf(s, w.y, a.y);
    return a;
}

// wcol = 16 x float2 = 32 VGPR (was 64): target 6+ waves/SIMD instead of 4.
__global__ __launch_bounds__(BLOCK, 6) void edge_attr_kernel(
    const float* __restrict__ pos,        // [N_NODES, 3]
    const int* __restrict__ ei,           // [2, N_EDGES] (harness delivers int32)
    const float* __restrict__ W,          // [DC, HIDDEN]
    const float* __restrict__ b,          // [HIDDEN]
    float* __restrict__ out)              // [N_EDGES, HIDDEN]
{
    __shared__ float dist_s[EPB];
    __shared__ float rbf_s[EPB][RBF_LD];

    const int tid = threadIdx.x;
    const int h2  = tid & 63;   // which float2 chunk of the 128 hidden cols
    const int wv  = tid >> 6;   // wave id 0..3 : edge-row offset

    // ---- W columns into registers (contiguous 512B/instr, L1/L2-hot)
    f32x2 wcol[DC];
    #pragma unroll
    for (int k = 0; k < DC; ++k)
        wcol[k] = *reinterpret_cast<const f32x2*>(W + k * HIDDEN + h2 * 2);
    const f32x2 bias = *reinterpret_cast<const f32x2*>(b + h2 * 2);

    const long row0 = (long)blockIdx.x * EPB;

    // ---- Phase 0: one dist per edge (waves 0,1 only; no duplicate gathers)
    if (tid < EPB) {
        const int e = (int)row0 + tid;
        const int s = ei[e];
        const int d = ei[N_EDGES + e];
        // 4B-aligned float4 covers the 12B row (+4B harmless overread within
        // the page-padded allocation); only xyz are used.
        const f32x4 ps = *reinterpret_cast<const f32x4u*>(pos + 3 * s);
        const f32x4 pd = *reinterpret_cast<const f32x4u*>(pos + 3 * d);
        const float dx = ps.x - pd.x;
        const float dy = ps.y - pd.y;
        const float dz = ps.z - pd.z;
        dist_s[tid] = sqrtf(dx * dx + dy * dy + dz * dz);
    }
    __syncthreads();

    // ---- Phase 1: RBF features, 8 centers per thread
    {
        const int el = tid & 127;
        const int kg = tid >> 7;          // 0 or 1 -> centers kg*8 .. kg*8+7
        const float dist = dist_s[el];    // stride-1 read, 2-way alias = free
        f32x4 r0, r1;
        #pragma unroll
        for (int j = 0; j < 4; ++j) {
            const float t = (dist - MU_STEP * (float)(kg * 8 + j)) * INV_SIGMA;
            r0[j] = __expf(-t * t);
        }
        #pragma unroll
        for (int j = 0; j < 4; ++j) {
            const float t = (dist - MU_STEP * (float)(kg * 8 + 4 + j)) * INV_SIGMA;
            r1[j] = __expf(-t * t);
        }
        *reinterpret_cast<f32x4*>(&rbf_s[el][kg * 8 + 0]) = r0;
        *reinterpret_cast<f32x4*>(&rbf_s[el][kg * 8 + 4]) = r1;
    }
    __syncthreads();

    // ---- Phase 2: out[e][h] = sigmoid(sum_k rbf[k] * W[k][h] + b[h])
    // wave wv handles rows el = wv + 4*i; one store instr = 512B contiguous row
    float* op = out + (row0 + wv) * HIDDEN + h2 * 2;
    #pragma unroll 4
    for (int i = 0; i < EPB / 4; ++i) {
        const int el = wv + i * 4;

        // 4x ds_read_b128, same address across the wave = broadcast (free)
        const f32x4* rp = reinterpret_cast<const f32x4*>(&rbf_s[el][0]);
        const f32x4 ra = rp[0];
        const f32x4 rb = rp[1];
        const f32x4 rc = rp[2];
        const f32x4 rd = rp[3];

        f32x2 acc = bias;
        acc = fma2(ra.x, wcol[0],  acc);
        acc = fma2(ra.y, wcol[1],  acc);
        acc = fma2(ra.z, wcol[2],  acc);
        acc = fma2(ra.w, wcol[3],  acc);
        acc = fma2(rb.x, wcol[4],  acc);
        acc = fma2(rb.y, wcol[5],  acc);
        acc = fma2(rb.z, wcol[6],  acc);
        acc = fma2(rb.w, wcol[7],  acc);
        acc = fma2(rc.x, wcol[8],  acc);
        acc = fma2(rc.y, wcol[9],  acc);
        acc = fma2(rc.z, wcol[10], acc);
        acc = fma2(rc.w, wcol[11], acc);
        acc = fma2(rd.x, wcol[12], acc);
        acc = fma2(rd.y, wcol[13], acc);
        acc = fma2(rd.z, wcol[14], acc);
        acc = fma2(rd.w, wcol[15], acc);

        f32x2 res;
        res.x = fast_sigmoid(acc.x);
        res.y = fast_sigmoid(acc.y);

        __builtin_nontemporal_store(res, reinterpret_cast<f32x2*>(op));
        op += 4 * HIDDEN;
    }
}

extern "C" void kernel_launch(void* const* d_in, const int* in_sizes, int n_in,
                              void* d_out, int out_size, void* d_ws, size_t ws_size,
                              hipStream_t stream) {
    const float* pos = (const float*)d_in[0];
    const int*   ei  = (const int*)d_in[1];     // harness delivers integers as int32
    const float* W   = (const float*)d_in[2];
    const float* b   = (const float*)d_in[3];
    float*       out = (float*)d_out;

    dim3 grid(N_EDGES / EPB);   // 1,600,000 / 128 = 12,500 blocks exactly
    edge_attr_kernel<<<grid, BLOCK, 0, stream>>>(pos, ei, W, b, out);
}